// Round 12
// baseline (147.392 us; speedup 1.0000x reference)
//
#include <hip/hip_runtime.h>
#include <hip/hip_bf16.h>

#define D    64    // feature dim == units
#define CH   4096  // edges per chunk (K1/K3)
#define BKT  32    // nodes per bucket (K4) — 1563 blocks ~ 6/CU
#define PASS 1024  // edges staged per pass in K4 (avg bucket = 512)

// ---------------------------------------------------------------------------
// K1: blocks [0, gemmTiles): Z = emb @ W (bf16 out).  Blocks [gemmTiles, +NC):
// per-chunk bucket histogram (native int LDS atomics) + per-edge local rank.
// ---------------------------------------------------------------------------
__global__ __launch_bounds__(256) void gemm_part(
    const float* __restrict__ emb,
    const float* __restrict__ W,
    __hip_bfloat16* __restrict__ Zb,
    const int*   __restrict__ dst,
    int*         __restrict__ histG,   // [NC * NB], chunk-major
    ushort*      __restrict__ lrank,   // [E]
    int N, int E, int NB, int gemmTiles)
{
    __shared__ int smem[4096];   // partition: hist[NB<=1563]; gemm: 64x64 tile

    if ((int)blockIdx.x >= gemmTiles) {
        const int c  = (int)blockIdx.x - gemmTiles;
        const int t  = threadIdx.x;
        for (int b = t; b < NB; b += 256) smem[b] = 0;
        __syncthreads();
        const int e0 = c * CH;
#pragma unroll
        for (int i = 0; i < 16; ++i) {
            int e = e0 + i * 256 + t;
            if (e < E) {
                int b = dst[e] / BKT;
                lrank[e] = (ushort)atomicAdd(&smem[b], 1);   // ds_add_rtn_u32
            }
        }
        __syncthreads();
        for (int b = t; b < NB; b += 256)
            histG[(size_t)c * NB + b] = smem[b];
        return;
    }

    const int lane = threadIdx.x & 63;
    const int wave = threadIdx.x >> 6;

    float wcol[D];
#pragma unroll
    for (int k = 0; k < D; ++k) wcol[k] = W[k * D + lane];

    float* At = (float*)smem;  // 64 x 64
    const int row0 = blockIdx.x * 64;

    for (int i = threadIdx.x; i < 1024; i += 256) {
        int r  = i >> 4;
        int gr = row0 + r;
        float4 v;
        if (gr < N) v = reinterpret_cast<const float4*>(emb)[(size_t)gr * 16 + (i & 15)];
        else        v = float4{0.f, 0.f, 0.f, 0.f};
        reinterpret_cast<float4*>(At)[i] = v;
    }
    __syncthreads();

    for (int rr = 0; rr < 16; ++rr) {
        int r  = wave * 16 + rr;
        int gr = row0 + r;
        if (gr >= N) break;
        const float4* arow = reinterpret_cast<const float4*>(At + r * D);
        float acc = 0.f;
#pragma unroll
        for (int k4 = 0; k4 < 16; ++k4) {
            float4 a = arow[k4];
            acc = fmaf(a.x, wcol[4 * k4 + 0], acc);
            acc = fmaf(a.y, wcol[4 * k4 + 1], acc);
            acc = fmaf(a.z, wcol[4 * k4 + 2], acc);
            acc = fmaf(a.w, wcol[4 * k4 + 3], acc);
        }
        Zb[(size_t)gr * D + lane] = __float2bfloat16(acc);
    }
}

// ---------------------------------------------------------------------------
// K2: exclusive scan over hist in BUCKET-MAJOR order (m = b*NC + c), values
// gathered from chunk-major histG.  4096 elems/block; partials <= 256
// inline-scanned by consumers.
// ---------------------------------------------------------------------------
__global__ __launch_bounds__(256) void scan_hist(
    const int* __restrict__ histG, int* __restrict__ offsets,
    int* __restrict__ partials, int NB, int NC, int M)
{
    __shared__ int sh[256];
    const int t    = threadIdx.x;
    const int base = blockIdx.x * 4096 + t * 16;

    int v[16], ps[16];
    int b = base / NC, c = base - b * NC;
#pragma unroll
    for (int k = 0; k < 16; ++k) {
        int m = base + k;
        v[k] = (m < M) ? histG[(size_t)c * NB + b] : 0;
        if (++c == NC) { c = 0; ++b; }
    }
    int s = 0;
#pragma unroll
    for (int k = 0; k < 16; ++k) { ps[k] = s; s += v[k]; }
    sh[t] = s;
    __syncthreads();
    for (int off = 1; off < 256; off <<= 1) {
        int x = (t >= off) ? sh[t - off] : 0;
        __syncthreads();
        sh[t] += x;
        __syncthreads();
    }
    const int excl = sh[t] - s;
#pragma unroll
    for (int k = 0; k < 4; ++k) {
        int4 o;
        o.x = excl + ps[4*k+0]; o.y = excl + ps[4*k+1];
        o.z = excl + ps[4*k+2]; o.w = excl + ps[4*k+3];
        reinterpret_cast<int4*>(offsets + base)[k] = o;
    }
    if (t == 255) partials[blockIdx.x] = sh[255];
}

__device__ __forceinline__ void scan_partials_lds256(
    const int* __restrict__ partials, int nb, int* sp)
{
    const int t    = threadIdx.x;
    const int orig = (t < nb) ? partials[t] : 0;
    sp[t] = orig;
    __syncthreads();
    for (int off = 1; off < 256; off <<= 1) {
        int x = (t >= off) ? sp[t - off] : 0;
        __syncthreads();
        sp[t] += x;
        __syncthreads();
    }
    int incl = sp[t];
    __syncthreads();
    sp[t] = incl - orig;  // exclusive
    __syncthreads();
}

// ---------------------------------------------------------------------------
// K3: scatter into bucket-grouped edge array (staged sorted in LDS, runs of
// consecutive global writes).  NO atomics.
// rec.x packs src (16 bits, N<65536) | (dst%32) << 16;  rec.y = w bits.
// ---------------------------------------------------------------------------
__global__ __launch_bounds__(256) void scatter_bkt(
    const int*    __restrict__ src,
    const int*    __restrict__ dst,
    const float*  __restrict__ w,
    const ushort* __restrict__ lrank,
    const int*    __restrict__ histG,
    const int*    __restrict__ offsets,
    const int*    __restrict__ partials,
    int2*         __restrict__ csr,
    int E, int NB, int NC, int nb2)
{
    __shared__ int2   rec[CH];      // 32 KB
    __shared__ ushort bidv[CH];     // 8 KB
    __shared__ int    delta[1568];
    __shared__ int    sh[256];
    __shared__ int    sp[256];
    scan_partials_lds256(partials, nb2, sp);

    const int t  = threadIdx.x;
    const int c  = blockIdx.x;
    const int e0 = c * CH;
    const int cnt = min(CH, E - e0);

    // local exclusive scan of this chunk's histogram (7 buckets per thread)
    int hv[7], hps[7];
    const int hbase = t * 7;
#pragma unroll
    for (int k = 0; k < 7; ++k) {
        int b = hbase + k;
        hv[k] = (b < NB) ? histG[(size_t)c * NB + b] : 0;
    }
    int s = 0;
#pragma unroll
    for (int k = 0; k < 7; ++k) { hps[k] = s; s += hv[k]; }
    sh[t] = s;
    __syncthreads();
    for (int off = 1; off < 256; off <<= 1) {
        int x = (t >= off) ? sh[t - off] : 0;
        __syncthreads();
        sh[t] += x;
        __syncthreads();
    }
    const int hexcl = sh[t] - s;
#pragma unroll
    for (int k = 0; k < 7; ++k) {
        int b = hbase + k;
        if (b < NB) delta[b] = hexcl + hps[k];   // localBase[b]
    }
    __syncthreads();

    // stage records sorted by bucket
#pragma unroll
    for (int i = 0; i < 16; ++i) {
        int e = e0 + i * 256 + t;
        if (e < E) {
            int d  = dst[e];
            int b  = d / BKT;
            int lp = delta[b] + lrank[e];
            rec[lp]  = make_int2(src[e] | ((d & (BKT - 1)) << 16), __float_as_int(w[e]));
            bidv[lp] = (ushort)b;
        }
    }
    __syncthreads();

    // delta[b] := globalChunkOff(b,c) - localBase[b]
#pragma unroll
    for (int k = 0; k < 7; ++k) {
        int b = hbase + k;
        if (b < NB) {
            int m = b * NC + c;
            delta[b] = offsets[m] + sp[m >> 12] - delta[b];
        }
    }
    __syncthreads();

    for (int j = t; j < cnt; j += 256)
        csr[j + delta[bidv[j]]] = rec[j];
}

// ---------------------------------------------------------------------------
// K4: one block per 32-node bucket (1563 blocks ~ 6/CU).  Per <=1024-edge
// pass: sort edges by node in LDS (native int atomics + 32-wide shfl scan),
// then each wave register-gathers its 8 nodes with 8 slots x 8 q-lanes:
// slot = lane>>3 walks the node's contiguous LDS list (8 edges in flight),
// q = lane&7 loads 16 B (int4 = 8 bf16) of the 128 B = EIGHT-int4 Z row.
// shfl_down reduce over slots; coalesced 256 B row store + relu.
// ---------------------------------------------------------------------------
__global__ __launch_bounds__(256) void aggregate(
    const __hip_bfloat16* __restrict__ Zb,
    const int2* __restrict__ csr,
    const int*  __restrict__ offsets,
    const int*  __restrict__ partials,
    float*      __restrict__ out,
    int N, int E, int NB, int NC, int nb2)
{
    __shared__ int2 srec[PASS];   // 8 KB
    __shared__ int  hist[BKT];
    __shared__ int  nbase[BKT + 1];
    __shared__ int  sp[256];
    scan_partials_lds256(partials, nb2, sp);

    const int t = threadIdx.x;
    const int b = blockIdx.x;

    const int m0 = b * NC;
    const int bStart = offsets[m0] + sp[m0 >> 12];
    int bEnd;
    if (b + 1 < NB) { int m1 = (b + 1) * NC; bEnd = offsets[m1] + sp[m1 >> 12]; }
    else            bEnd = E;

    const int wv   = t >> 6;
    const int lane = t & 63;
    const int slot = lane >> 3;   // 0..7
    const int q    = lane & 7;    // 0..7 — int4 index within the 8-int4 row

    const int4* Zq = reinterpret_cast<const int4*>(Zb);   // row = 8 int4 (128 B)

    // acc[r] = 8 floats (lo4, hi4) for node wv*8 + r
    float4 alo[8], ahi[8];
#pragma unroll
    for (int r = 0; r < 8; ++r) { alo[r] = float4{0,0,0,0}; ahi[r] = float4{0,0,0,0}; }

    for (int cur = bStart; cur < bEnd; cur += PASS) {
        const int cnt = min(PASS, bEnd - cur);

        if (t < BKT) hist[t] = 0;
        __syncthreads();

        // load + local rank (<=4 edges/thread, static register indexing)
        int2 myrec[4]; int mypos[4];
#pragma unroll
        for (int k = 0; k < 4; ++k) {
            int j = k * 256 + t;
            if (j < cnt) {
                int2 r2 = csr[cur + j];
                myrec[k] = r2;
                mypos[k] = atomicAdd(&hist[(r2.x >> 16) & (BKT - 1)], 1);
            }
        }
        __syncthreads();

        // exclusive scan of 32-entry hist (first 32 lanes)
        if (t < BKT) {
            int v = hist[t];
            int x = v;
            for (int off = 1; off < BKT; off <<= 1) {
                int y = __shfl_up(x, off, 64);
                if (t >= off) x += y;
            }
            nbase[t] = x - v;
            if (t == BKT - 1) nbase[BKT] = x;   // == cnt
        }
        __syncthreads();

        // scatter into node-sorted LDS
#pragma unroll
        for (int k = 0; k < 4; ++k) {
            int j = k * 256 + t;
            if (j < cnt)
                srec[nbase[(myrec[k].x >> 16) & (BKT - 1)] + mypos[k]] = myrec[k];
        }
        __syncthreads();

        // register gather: wave wv owns nodes [wv*8, wv*8+8)
        for (int r = 0; r < 8; ++r) {
            const int nl = wv * 8 + r;
            const int je = nbase[nl + 1];
            for (int j = nbase[nl] + slot; j < je; j += 8) {
                int2  e  = srec[j];
                float ww = __int_as_float(e.y);
                int   sn = e.x & 0xFFFF;
                int4  zz = Zq[(size_t)sn * 8 + q];   // FIX: 8 int4 per row
                alo[r].x = fmaf(ww, __uint_as_float((unsigned)zz.x << 16),          alo[r].x);
                alo[r].y = fmaf(ww, __uint_as_float((unsigned)zz.x & 0xFFFF0000u),  alo[r].y);
                alo[r].z = fmaf(ww, __uint_as_float((unsigned)zz.y << 16),          alo[r].z);
                alo[r].w = fmaf(ww, __uint_as_float((unsigned)zz.y & 0xFFFF0000u),  alo[r].w);
                ahi[r].x = fmaf(ww, __uint_as_float((unsigned)zz.z << 16),          ahi[r].x);
                ahi[r].y = fmaf(ww, __uint_as_float((unsigned)zz.z & 0xFFFF0000u),  ahi[r].y);
                ahi[r].z = fmaf(ww, __uint_as_float((unsigned)zz.w << 16),          ahi[r].z);
                ahi[r].w = fmaf(ww, __uint_as_float((unsigned)zz.w & 0xFFFF0000u),  ahi[r].w);
            }
        }
        __syncthreads();   // protect srec before next pass
    }

    // reduce the 8 slots + store (8 lanes x 32 B = coalesced 256 B row)
    const int node0 = b * BKT + wv * 8;
#pragma unroll
    for (int r = 0; r < 8; ++r) {
        float4 lo = alo[r], hi = ahi[r];
#pragma unroll
        for (int off = 32; off >= 8; off >>= 1) {
            lo.x += __shfl_down(lo.x, off, 64);
            lo.y += __shfl_down(lo.y, off, 64);
            lo.z += __shfl_down(lo.z, off, 64);
            lo.w += __shfl_down(lo.w, off, 64);
            hi.x += __shfl_down(hi.x, off, 64);
            hi.y += __shfl_down(hi.y, off, 64);
            hi.z += __shfl_down(hi.z, off, 64);
            hi.w += __shfl_down(hi.w, off, 64);
        }
        int node = node0 + r;
        if (lane < 8 && node < N) {
            float4 o0, o1;
            o0.x = fmaxf(lo.x, 0.f); o0.y = fmaxf(lo.y, 0.f);
            o0.z = fmaxf(lo.z, 0.f); o0.w = fmaxf(lo.w, 0.f);
            o1.x = fmaxf(hi.x, 0.f); o1.y = fmaxf(hi.y, 0.f);
            o1.z = fmaxf(hi.z, 0.f); o1.w = fmaxf(hi.w, 0.f);
            float4* orow = reinterpret_cast<float4*>(out) + (size_t)node * 16 + lane * 2;
            orow[0] = o0;
            orow[1] = o1;
        }
    }
}

// ---------------------------------------------------------------------------
extern "C" void kernel_launch(void* const* d_in, const int* in_sizes, int n_in,
                              void* d_out, int out_size, void* d_ws, size_t ws_size,
                              hipStream_t stream)
{
    const float* emb  = (const float*)d_in[0];  // [N, 64]
    const int*   esrc = (const int*)  d_in[1];  // [E]
    const int*   edst = (const int*)  d_in[2];  // [E]
    const float* ew   = (const float*)d_in[3];  // [E]
    const float* W    = (const float*)d_in[4];  // [64, 64]
    float*       out  = (float*)d_out;          // [N, 64]

    const int N  = in_sizes[0] / D;
    const int E  = in_sizes[1];

    const int NB  = (N + BKT - 1) / BKT;  // 1563 buckets of 32 nodes
    const int NC  = (E + CH - 1) / CH;    // 196 chunks
    const int M   = NB * NC;              // 306,348 scan elements
    const int nb2 = (M + 4095) / 4096;    // 75 scan blocks (<= 256)
    const int Mpad = nb2 * 4096;

    // Workspace (~17 MB), all segments 16 B aligned.
    char* p = (char*)d_ws;
    __hip_bfloat16* Zb = (__hip_bfloat16*)p;  p += (size_t)N * D * 2;   // 6.4 MB
    int*    histG   = (int*)p;                p += (size_t)Mpad * 4;    // 1.2 MB
    int*    offsets = (int*)p;                p += (size_t)Mpad * 4;    // 1.2 MB
    int*    partials= (int*)p;                p += 256 * 4;
    ushort* lrank   = (ushort*)p;             p += (size_t)((E + 7) & ~7) * 2; // 1.6 MB
    int2*   csr     = (int2*)p;                                         // 6.4 MB

    const int gemmTiles = (N + 63) / 64;
    gemm_part<<<gemmTiles + NC, 256, 0, stream>>>(
        emb, W, Zb, edst, histG, lrank, N, E, NB, gemmTiles);

    scan_hist<<<nb2, 256, 0, stream>>>(histG, offsets, partials, NB, NC, M);

    scatter_bkt<<<NC, 256, 0, stream>>>(
        esrc, edst, ew, lrank, histG, offsets, partials, csr, E, NB, NC, nb2);

    aggregate<<<NB, 256, 0, stream>>>(
        Zb, csr, offsets, partials, out, N, E, NB, NC, nb2);
}